// Round 1
// baseline (3432.870 us; speedup 1.0000x reference)
//
#include <hip/hip_runtime.h>
#include <hip/hip_bf16.h>
#include <math.h>

#define V_   32000
#define L_   4
#define H_   4
#define D_   256
#define DF_  1024
#define B_   2
#define T_   2048
#define DH_  64
#define NTOK (B_*T_)   // 4096

// ---------------- embedding: x = tok_emb[idx] + pos_emb[:T] ----------------
__global__ void embed_kernel(const int* __restrict__ idx, const float* __restrict__ tok,
                             const float* __restrict__ pos, float* __restrict__ x) {
    int n = blockIdx.x;          // token 0..NTOK-1
    int d = threadIdx.x;         // 0..255
    int t = n % T_;
    int id = idx[n];
    x[(size_t)n*D_ + d] = tok[(size_t)id*D_ + d] + pos[(size_t)t*D_ + d];
}

// ---------------- layernorm over D=256, one block per row ----------------
__global__ void ln_kernel(const float* __restrict__ x, const float* __restrict__ g,
                          const float* __restrict__ bta, float* __restrict__ out) {
    int n = blockIdx.x;
    int d = threadIdx.x;
    float v = x[(size_t)n*D_ + d];
    __shared__ float red[4];
    float s = v;
    #pragma unroll
    for (int o = 32; o >= 1; o >>= 1) s += __shfl_xor(s, o);
    int wave = d >> 6, lane = d & 63;
    if (lane == 0) red[wave] = s;
    __syncthreads();
    float mu = (red[0] + red[1] + red[2] + red[3]) * (1.0f / D_);
    float c = v - mu;
    float s2 = c * c;
    #pragma unroll
    for (int o = 32; o >= 1; o >>= 1) s2 += __shfl_xor(s2, o);
    __syncthreads();
    if (lane == 0) red[wave] = s2;
    __syncthreads();
    float var = (red[0] + red[1] + red[2] + red[3]) * (1.0f / D_);
    out[(size_t)n*D_ + d] = c * rsqrtf(var + 1e-5f) * g[d] + bta[d];
}

// ---------------- GEMM: C[M,N] = A[M,K] @ W[K,N] + bias ----------------
// MODE 0: plain         MODE 1: write q/k/v transposed to [B,H,T,DH]
// MODE 2: + residual    MODE 3: exact GELU
template<int MODE>
__global__ __launch_bounds__(256) void gemm_kernel(
    const float* __restrict__ A, const float* __restrict__ W,
    const float* __restrict__ bias, const float* __restrict__ res,
    float* __restrict__ C, int M, int N, int K)
{
    __shared__ float As[16][68];   // padded: write 2-way, float4 read ok (272B rows, 16B aligned)
    __shared__ float Ws[16][64];
    int tid = threadIdx.x;
    int row0 = blockIdx.y * 64, col0 = blockIdx.x * 64;
    int tx = tid & 15, ty = tid >> 4;
    float acc[4][4] = {};

    for (int k0 = 0; k0 < K; k0 += 16) {
        __syncthreads();
        #pragma unroll
        for (int i = 0; i < 4; i++) {
            int idx = tid + i * 256;
            int r = idx >> 4, c = idx & 15;        // A tile: 64 rows x 16 cols
            As[c][r] = A[(size_t)(row0 + r) * K + k0 + c];
            int r2 = idx >> 6, c2 = idx & 63;      // W tile: 16 rows x 64 cols
            Ws[r2][c2] = W[(size_t)(k0 + r2) * N + col0 + c2];
        }
        __syncthreads();
        #pragma unroll
        for (int kk = 0; kk < 16; kk++) {
            const float4 a = *(const float4*)(&As[kk][ty * 4]);
            const float4 w = *(const float4*)(&Ws[kk][tx * 4]);
            float av[4] = {a.x, a.y, a.z, a.w};
            float wv[4] = {w.x, w.y, w.z, w.w};
            #pragma unroll
            for (int i = 0; i < 4; i++)
                #pragma unroll
                for (int j = 0; j < 4; j++)
                    acc[i][j] += av[i] * wv[j];
        }
    }

    #pragma unroll
    for (int i = 0; i < 4; i++) {
        int row = row0 + ty * 4 + i;
        #pragma unroll
        for (int j = 0; j < 4; j++) {
            int col = col0 + tx * 4 + j;
            float v = acc[i][j] + bias[col];
            if (MODE == 2) v += res[(size_t)row * N + col];
            if (MODE == 3) v = 0.5f * v * (1.0f + erff(v * 0.70710678118f));
            if (MODE == 1) {
                int bb = row / T_, t = row % T_;
                int h = col >> 6, dh = col & 63;
                C[(((size_t)(bb * H_ + h)) * T_ + t) * DH_ + dh] = v;
            } else {
                C[(size_t)row * N + col] = v;
            }
        }
    }
}

// ---------------- causal flash attention ----------------
// grid (T/64, B*H). block 256: 4 threads per query row, 16 dh each.
__global__ __launch_bounds__(256) void attn_kernel(
    const float* __restrict__ q, const float* __restrict__ k,
    const float* __restrict__ v, float* __restrict__ y)
{
    int qb = blockIdx.x;
    int bh = blockIdx.y;
    int bidx = bh >> 2;     // / H_
    int h = bh & 3;         // % H_
    const float* qp = q + (size_t)bh * T_ * DH_;
    const float* kp = k + (size_t)bh * T_ * DH_;
    const float* vp = v + (size_t)bh * T_ * DH_;

    __shared__ float Qs[64][68];
    __shared__ float Ks[64][68];
    __shared__ float Vs[64][68];
    __shared__ float Ps[64][68];

    int tid = threadIdx.x;
    int qi = tid >> 2;      // 0..63
    int part = tid & 3;     // 0..3

    #pragma unroll
    for (int i = 0; i < 16; i++) {
        int idx = i * 256 + tid;
        int r = idx >> 6, c = idx & 63;
        Qs[r][c] = qp[(size_t)(qb * 64 + r) * DH_ + c];
    }

    float m = -1e30f, l = 0.0f;
    float o[16];
    #pragma unroll
    for (int i = 0; i < 16; i++) o[i] = 0.0f;
    const float scale = 0.125f;   // 1/sqrt(64)

    for (int kc = 0; kc <= qb; kc++) {
        __syncthreads();
        #pragma unroll
        for (int i = 0; i < 16; i++) {
            int idx = i * 256 + tid;
            int r = idx >> 6, c = idx & 63;
            Ks[r][c] = kp[(size_t)(kc * 64 + r) * DH_ + c];
            Vs[r][c] = vp[(size_t)(kc * 64 + r) * DH_ + c];
        }
        __syncthreads();

        float sc[16];
        float chmax = -1e30f;
        #pragma unroll
        for (int jj = 0; jj < 16; jj++) {
            int kj = part * 16 + jj;
            float s = 0.0f;
            #pragma unroll 8
            for (int d0 = 0; d0 < 64; d0++)
                s += Qs[qi][d0] * Ks[kj][d0];
            s *= scale;
            if (kc == qb && kj > qi) s = -1e30f;
            sc[jj] = s;
            chmax = fmaxf(chmax, s);
        }
        chmax = fmaxf(chmax, __shfl_xor(chmax, 1));
        chmax = fmaxf(chmax, __shfl_xor(chmax, 2));
        float newm = fmaxf(m, chmax);
        float f = __expf(m - newm);
        float psum = 0.0f;
        #pragma unroll
        for (int jj = 0; jj < 16; jj++) {
            float p = __expf(sc[jj] - newm);
            Ps[qi][part * 16 + jj] = p;
            psum += p;
        }
        psum += __shfl_xor(psum, 1);
        psum += __shfl_xor(psum, 2);
        l = l * f + psum;
        m = newm;
        #pragma unroll
        for (int i = 0; i < 16; i++) o[i] *= f;
        __syncthreads();

        for (int jj = 0; jj < 64; jj++) {
            float p = Ps[qi][jj];
            #pragma unroll
            for (int i = 0; i < 16; i++)
                o[i] += p * Vs[jj][part * 16 + i];
        }
    }

    float inv = 1.0f / l;
    int tglob = qb * 64 + qi;
    size_t base = ((size_t)(bidx * T_ + tglob)) * D_ + h * DH_ + part * 16;
    #pragma unroll
    for (int i = 0; i < 16; i++)
        y[base + i] = o[i] * inv;
}

// ---------------- host launch ----------------
extern "C" void kernel_launch(void* const* d_in, const int* in_sizes, int n_in,
                              void* d_out, int out_size, void* d_ws, size_t ws_size,
                              hipStream_t stream)
{
    const int*   idx  = (const int*)d_in[0];
    const float* tok  = (const float*)d_in[1];
    const float* pos  = (const float*)d_in[2];
    const float* Wq   = (const float*)d_in[3];
    const float* bq   = (const float*)d_in[4];
    const float* Wk   = (const float*)d_in[5];
    const float* bk   = (const float*)d_in[6];
    const float* Wv   = (const float*)d_in[7];
    const float* bv   = (const float*)d_in[8];
    const float* Wo   = (const float*)d_in[9];
    const float* bo   = (const float*)d_in[10];
    const float* ln1g = (const float*)d_in[11];
    const float* ln1b = (const float*)d_in[12];
    const float* W1   = (const float*)d_in[13];
    const float* b1   = (const float*)d_in[14];
    const float* W2   = (const float*)d_in[15];
    const float* b2   = (const float*)d_in[16];
    const float* ln2g = (const float*)d_in[17];
    const float* ln2b = (const float*)d_in[18];
    const float* lnfg = (const float*)d_in[19];
    const float* lnfb = (const float*)d_in[20];
    const float* hW   = (const float*)d_in[21];
    const float* hb   = (const float*)d_in[22];

    float* x    = (float*)d_ws;                       // NTOK*D
    float* hbuf = x    + (size_t)NTOK * D_;           // NTOK*D
    float* qbuf = hbuf + (size_t)NTOK * D_;           // NTOK*D  ([B,H,T,DH])
    float* kbuf = qbuf + (size_t)NTOK * D_;
    float* vbuf = kbuf + (size_t)NTOK * D_;
    float* ybuf = vbuf + (size_t)NTOK * D_;           // NTOK*D
    float* ff   = ybuf + (size_t)NTOK * D_;           // NTOK*DF

    embed_kernel<<<NTOK, 256, 0, stream>>>(idx, tok, pos, x);

    dim3 gProj(D_ / 64, NTOK / 64);
    dim3 gFF1(DF_ / 64, NTOK / 64);
    dim3 gHead(V_ / 64, NTOK / 64);
    dim3 gAttn(T_ / 64, B_ * H_);

    for (int l = 0; l < L_; l++) {
        ln_kernel<<<NTOK, 256, 0, stream>>>(x, ln1g + l * D_, ln1b + l * D_, hbuf);
        gemm_kernel<1><<<gProj, 256, 0, stream>>>(hbuf, Wq + (size_t)l * D_ * D_, bq + l * D_, nullptr, qbuf, NTOK, D_, D_);
        gemm_kernel<1><<<gProj, 256, 0, stream>>>(hbuf, Wk + (size_t)l * D_ * D_, bk + l * D_, nullptr, kbuf, NTOK, D_, D_);
        gemm_kernel<1><<<gProj, 256, 0, stream>>>(hbuf, Wv + (size_t)l * D_ * D_, bv + l * D_, nullptr, vbuf, NTOK, D_, D_);
        attn_kernel<<<gAttn, 256, 0, stream>>>(qbuf, kbuf, vbuf, ybuf);
        gemm_kernel<2><<<gProj, 256, 0, stream>>>(ybuf, Wo + (size_t)l * D_ * D_, bo + l * D_, x, x, NTOK, D_, D_);
        ln_kernel<<<NTOK, 256, 0, stream>>>(x, ln2g + l * D_, ln2b + l * D_, hbuf);
        gemm_kernel<3><<<gFF1, 256, 0, stream>>>(hbuf, W1 + (size_t)l * D_ * DF_, b1 + l * DF_, nullptr, ff, NTOK, DF_, D_);
        gemm_kernel<2><<<gProj, 256, 0, stream>>>(ff, W2 + (size_t)l * DF_ * D_, b2 + l * D_, x, x, NTOK, D_, DF_);
    }

    ln_kernel<<<NTOK, 256, 0, stream>>>(x, lnfg, lnfb, hbuf);
    gemm_kernel<0><<<gHead, 256, 0, stream>>>(hbuf, hW, hb, nullptr, (float*)d_out, NTOK, V_, D_);
}

// Round 2
// 836.540 us; speedup vs baseline: 4.1037x; 4.1037x over previous
//
#include <hip/hip_runtime.h>
#include <hip/hip_bf16.h>
#include <math.h>

#define V_   32000
#define L_   4
#define H_   4
#define D_   256
#define DF_  1024
#define B_   2
#define T_   2048
#define DH_  64
#define NTOK (B_*T_)   // 4096

typedef __attribute__((ext_vector_type(8))) short bf16x8;
typedef __attribute__((ext_vector_type(4))) float f32x4;
typedef unsigned short u16;

#define GLOAD16(gsrc, ldst) \
  __builtin_amdgcn_global_load_lds((const __attribute__((address_space(1))) void*)(gsrc), \
                                   (__attribute__((address_space(3))) void*)(ldst), 16, 0, 0)

__device__ __forceinline__ u16 f2bf(float f) {
    unsigned int u = __builtin_bit_cast(unsigned int, f);
    u = (u + 0x7fff + ((u >> 16) & 1)) >> 16;   // RNE
    return (u16)u;
}

// ---------------- embedding: x = tok_emb[idx] + pos_emb[:T] (f32) ----------------
__global__ void embed_kernel(const int* __restrict__ idx, const float* __restrict__ tok,
                             const float* __restrict__ pos, float* __restrict__ x) {
    int n = blockIdx.x;
    int d = threadIdx.x;
    int t = n % T_;
    int id = idx[n];
    x[(size_t)n*D_ + d] = tok[(size_t)id*D_ + d] + pos[(size_t)t*D_ + d];
}

// ---------------- layernorm f32 in -> bf16 out ----------------
__global__ void ln_kernel(const float* __restrict__ x, const float* __restrict__ g,
                          const float* __restrict__ bta, u16* __restrict__ out) {
    int n = blockIdx.x;
    int d = threadIdx.x;
    float v = x[(size_t)n*D_ + d];
    __shared__ float red[4];
    float s = v;
    #pragma unroll
    for (int o = 32; o >= 1; o >>= 1) s += __shfl_xor(s, o);
    int wave = d >> 6, lane = d & 63;
    if (lane == 0) red[wave] = s;
    __syncthreads();
    float mu = (red[0] + red[1] + red[2] + red[3]) * (1.0f / D_);
    float c = v - mu;
    float s2 = c * c;
    #pragma unroll
    for (int o = 32; o >= 1; o >>= 1) s2 += __shfl_xor(s2, o);
    __syncthreads();
    if (lane == 0) red[wave] = s2;
    __syncthreads();
    float var = (red[0] + red[1] + red[2] + red[3]) * (1.0f / D_);
    out[(size_t)n*D_ + d] = f2bf(c * rsqrtf(var + 1e-5f) * g[d] + bta[d]);
}

// ---------------- weight prep: W[K,N] f32 -> WT[N,K] bf16, grid.z = layer ----------------
__global__ __launch_bounds__(256) void twb_kernel(const float* __restrict__ src,
                                                  u16* __restrict__ dst, int K, int N) {
    int z = blockIdx.z;
    src += (size_t)z * K * N;
    dst += (size_t)z * K * N;
    __shared__ float tile[32][33];
    int k0 = blockIdx.y * 32, n0 = blockIdx.x * 32;
    int tc = threadIdx.x & 31, tr = threadIdx.x >> 5;   // tr 0..7
    #pragma unroll
    for (int i = 0; i < 4; i++)
        tile[tr + i*8][tc] = src[(size_t)(k0 + tr + i*8) * N + n0 + tc];
    __syncthreads();
    #pragma unroll
    for (int i = 0; i < 4; i++)
        dst[(size_t)(n0 + tr + i*8) * K + k0 + tc] = f2bf(tile[tc][tr + i*8]);
}

// ---------------- MFMA GEMM: C[M,N] = A[M,K](bf16) @ WT[N,K](bf16)^T + bias ----------------
// MODE 0: f32 out    MODE 1: bf16 out, scattered to [B,H,T,DH]
// MODE 2: f32 out + residual    MODE 3: bf16 out, exact GELU
template<int MODE>
__global__ __launch_bounds__(256) void mfma_gemm(
    const u16* __restrict__ A, const u16* __restrict__ BT,
    const float* __restrict__ bias, const float* res,
    void* Cout, int M, int N, int K)
{
    __shared__ u16 As[128*64];
    __shared__ u16 Bs[128*64];
    int tid = threadIdx.x;
    int lane = tid & 63, w = tid >> 6;
    int lr = lane & 15, lg = lane >> 4;
    int wm = w >> 1, wn = w & 1;

    // XCD-aware bijective swizzle (all our grids have nwg % 8 == 0)
    int gx = gridDim.x;
    int nwg = gx * gridDim.y;
    int orig = blockIdx.y * gx + blockIdx.x;
    int bid = ((nwg & 7) == 0) ? ((orig & 7) * (nwg >> 3) + (orig >> 3)) : orig;
    int row0 = (bid / gx) * 128, col0 = (bid % gx) * 128;

    f32x4 acc[4][4] = {};

    for (int k0 = 0; k0 < K; k0 += 64) {
        __syncthreads();
        #pragma unroll
        for (int i = 0; i < 4; i++) {
            int o16 = tid + i * 256;          // 16B-chunk index within 16KB tile
            int r = o16 >> 3;                 // LDS row (128B rows)
            int slot = (o16 & 7) << 4;        // byte slot in row
            int sw = slot ^ ((r & 7) << 4);   // swizzled source column-byte
            GLOAD16(A  + (size_t)(row0 + r) * K + k0 + (sw >> 1), &As[o16 * 8]);
            GLOAD16(BT + (size_t)(col0 + r) * K + k0 + (sw >> 1), &Bs[o16 * 8]);
        }
        __syncthreads();
        #pragma unroll
        for (int ks = 0; ks < 2; ks++) {
            bf16x8 af[4], bfg[4];
            #pragma unroll
            for (int mi = 0; mi < 4; mi++) {
                int rr = wm * 64 + mi * 16 + lr;
                af[mi] = *(const bf16x8*)(As + rr * 64 + (((ks * 64 + lg * 16) ^ ((rr & 7) << 4)) >> 1));
            }
            #pragma unroll
            for (int ni = 0; ni < 4; ni++) {
                int rr = wn * 64 + ni * 16 + lr;
                bfg[ni] = *(const bf16x8*)(Bs + rr * 64 + (((ks * 64 + lg * 16) ^ ((rr & 7) << 4)) >> 1));
            }
            #pragma unroll
            for (int mi = 0; mi < 4; mi++)
                #pragma unroll
                for (int ni = 0; ni < 4; ni++)
                    acc[mi][ni] = __builtin_amdgcn_mfma_f32_16x16x32_bf16(af[mi], bfg[ni], acc[mi][ni], 0, 0, 0);
        }
    }

    #pragma unroll
    for (int mi = 0; mi < 4; mi++) {
        #pragma unroll
        for (int ni = 0; ni < 4; ni++) {
            #pragma unroll
            for (int j = 0; j < 4; j++) {
                int row = row0 + wm * 64 + mi * 16 + lg * 4 + j;
                int col = col0 + wn * 64 + ni * 16 + lr;
                float v = acc[mi][ni][j] + bias[col];
                if (MODE == 0) {
                    ((float*)Cout)[(size_t)row * N + col] = v;
                } else if (MODE == 2) {
                    ((float*)Cout)[(size_t)row * N + col] = v + res[(size_t)row * N + col];
                } else if (MODE == 3) {
                    v = 0.5f * v * (1.0f + erff(v * 0.70710678118f));
                    ((u16*)Cout)[(size_t)row * N + col] = f2bf(v);
                } else {   // MODE 1: scatter to [B,H,T,DH]
                    int bb = row >> 11, t = row & (T_ - 1);
                    int h = col >> 6, dh = col & 63;
                    ((u16*)Cout)[((((size_t)bb * H_ + h) * T_) + t) * DH_ + dh] = f2bf(v);
                }
            }
        }
    }
}

// ---------------- MFMA causal flash attention ----------------
// grid (T/64, B*H), block 256 = 4 waves x 16 q-rows
__global__ __launch_bounds__(256) void attn_kernel(
    const u16* __restrict__ q, const u16* __restrict__ k,
    const u16* __restrict__ v, u16* __restrict__ y)
{
    int qb = blockIdx.x;
    int bh = blockIdx.y;
    int bidx = bh >> 2, h = bh & 3;
    const u16* qp = q + (size_t)bh * T_ * DH_;
    const u16* kp = k + (size_t)bh * T_ * DH_;
    const u16* vp = v + (size_t)bh * T_ * DH_;

    __shared__ u16 Qs[64*64];
    __shared__ u16 Ks[64*64];
    __shared__ u16 VT[64*72];      // V transposed [dh][key], pad 72
    __shared__ u16 Ps[4][16*72];   // per-wave P tile [q][key], pad 72

    int tid = threadIdx.x;
    int lane = tid & 63, w = tid >> 6;
    int lr = lane & 15, lg = lane >> 4;

    // stage Q once (swizzled source, linear LDS)
    #pragma unroll
    for (int i = 0; i < 2; i++) {
        int o16 = tid + i * 256;
        int r = o16 >> 3;
        int slot = (o16 & 7) << 4;
        int sw = slot ^ ((r & 7) << 4);
        GLOAD16(qp + (size_t)(qb * 64 + r) * DH_ + (sw >> 1), &Qs[o16 * 8]);
    }
    int vkey = tid & 63;            // lane -> key (conflict-free VT writes)
    int vdh0 = (tid >> 6) * 8;
    __syncthreads();

    bf16x8 qa[2];
    #pragma unroll
    for (int ks = 0; ks < 2; ks++) {
        int rr = w * 16 + lr;
        qa[ks] = *(const bf16x8*)(Qs + rr * 64 + (((ks * 64 + lg * 16) ^ ((rr & 7) << 4)) >> 1));
    }

    float m[4], lden[4];
    f32x4 o[4] = {};
    #pragma unroll
    for (int j = 0; j < 4; j++) { m[j] = -1e30f; lden[j] = 0.0f; }

    for (int kc = 0; kc <= qb; kc++) {
        __syncthreads();
        #pragma unroll
        for (int i = 0; i < 2; i++) {
            int o16 = tid + i * 256;
            int r = o16 >> 3;
            int slot = (o16 & 7) << 4;
            int sw = slot ^ ((r & 7) << 4);
            GLOAD16(kp + (size_t)(kc * 64 + r) * DH_ + (sw >> 1), &Ks[o16 * 8]);
        }
        #pragma unroll
        for (int half = 0; half < 2; half++) {   // V register transpose
            int dh0 = vdh0 + half * 32;
            bf16x8 vv = *(const bf16x8*)(vp + (size_t)(kc * 64 + vkey) * DH_ + dh0);
            #pragma unroll
            for (int e = 0; e < 8; e++)
                VT[(dh0 + e) * 72 + vkey] = (u16)vv[e];
        }
        __syncthreads();

        // S = Q K^T  (4 col tiles of 16 keys)
        f32x4 sc[4];
        #pragma unroll
        for (int ct = 0; ct < 4; ct++) {
            f32x4 s = {};
            #pragma unroll
            for (int ks = 0; ks < 2; ks++) {
                int rr = ct * 16 + lr;
                bf16x8 kb = *(const bf16x8*)(Ks + rr * 64 + (((ks * 64 + lg * 16) ^ ((rr & 7) << 4)) >> 1));
                s = __builtin_amdgcn_mfma_f32_16x16x32_bf16(qa[ks], kb, s, 0, 0, 0);
            }
            sc[ct] = s;
        }
        // scale + causal mask + row max
        float mloc[4];
        #pragma unroll
        for (int j = 0; j < 4; j++) mloc[j] = -1e30f;
        #pragma unroll
        for (int ct = 0; ct < 4; ct++)
            #pragma unroll
            for (int j = 0; j < 4; j++) {
                float s = sc[ct][j] * 0.125f;
                if (kc == qb && (ct * 16 + lr) > (w * 16 + lg * 4 + j)) s = -1e30f;
                sc[ct][j] = s;
                mloc[j] = fmaxf(mloc[j], s);
            }
        #pragma unroll
        for (int j = 0; j < 4; j++) {
            mloc[j] = fmaxf(mloc[j], __shfl_xor(mloc[j], 1));
            mloc[j] = fmaxf(mloc[j], __shfl_xor(mloc[j], 2));
            mloc[j] = fmaxf(mloc[j], __shfl_xor(mloc[j], 4));
            mloc[j] = fmaxf(mloc[j], __shfl_xor(mloc[j], 8));
        }
        float f[4], rs[4];
        #pragma unroll
        for (int j = 0; j < 4; j++) {
            float nm = fmaxf(m[j], mloc[j]);
            f[j] = __expf(m[j] - nm);
            m[j] = nm;
            rs[j] = 0.0f;
        }
        #pragma unroll
        for (int ct = 0; ct < 4; ct++)
            #pragma unroll
            for (int j = 0; j < 4; j++) {
                float p = __expf(sc[ct][j] - m[j]);
                rs[j] += p;
                Ps[w][(lg * 4 + j) * 72 + ct * 16 + lr] = f2bf(p);
            }
        #pragma unroll
        for (int j = 0; j < 4; j++) {
            rs[j] += __shfl_xor(rs[j], 1);
            rs[j] += __shfl_xor(rs[j], 2);
            rs[j] += __shfl_xor(rs[j], 4);
            rs[j] += __shfl_xor(rs[j], 8);
            lden[j] = lden[j] * f[j] + rs[j];
        }
        #pragma unroll
        for (int dt = 0; dt < 4; dt++)
            #pragma unroll
            for (int j = 0; j < 4; j++)
                o[dt][j] *= f[j];
        // O += P V   (P from per-wave LDS, V from transposed tile)
        #pragma unroll
        for (int ks = 0; ks < 2; ks++) {
            bf16x8 pa = *(const bf16x8*)(&Ps[w][lr * 72 + ks * 32 + lg * 8]);
            #pragma unroll
            for (int dt = 0; dt < 4; dt++) {
                bf16x8 vb = *(const bf16x8*)(&VT[(dt * 16 + lr) * 72 + ks * 32 + lg * 8]);
                o[dt] = __builtin_amdgcn_mfma_f32_16x16x32_bf16(pa, vb, o[dt], 0, 0, 0);
            }
        }
    }

    #pragma unroll
    for (int j = 0; j < 4; j++) {
        float inv = 1.0f / lden[j];
        int q_g = qb * 64 + w * 16 + lg * 4 + j;
        size_t base = ((size_t)(bidx * T_ + q_g)) * D_ + h * DH_;
        #pragma unroll
        for (int dt = 0; dt < 4; dt++)
            y[base + dt * 16 + lr] = f2bf(o[dt][j] * inv);
    }
}

// ---------------- host launch ----------------
extern "C" void kernel_launch(void* const* d_in, const int* in_sizes, int n_in,
                              void* d_out, int out_size, void* d_ws, size_t ws_size,
                              hipStream_t stream)
{
    const int*   idx  = (const int*)d_in[0];
    const float* tok  = (const float*)d_in[1];
    const float* pos  = (const float*)d_in[2];
    const float* Wq   = (const float*)d_in[3];
    const float* bq   = (const float*)d_in[4];
    const float* Wk   = (const float*)d_in[5];
    const float* bk   = (const float*)d_in[6];
    const float* Wv   = (const float*)d_in[7];
    const float* bv   = (const float*)d_in[8];
    const float* Wo   = (const float*)d_in[9];
    const float* bo   = (const float*)d_in[10];
    const float* ln1g = (const float*)d_in[11];
    const float* ln1b = (const float*)d_in[12];
    const float* W1   = (const float*)d_in[13];
    const float* b1   = (const float*)d_in[14];
    const float* W2   = (const float*)d_in[15];
    const float* b2   = (const float*)d_in[16];
    const float* ln2g = (const float*)d_in[17];
    const float* ln2b = (const float*)d_in[18];
    const float* lnfg = (const float*)d_in[19];
    const float* lnfb = (const float*)d_in[20];
    const float* hW   = (const float*)d_in[21];
    const float* hb   = (const float*)d_in[22];

    char* p = (char*)d_ws;
    float* x    = (float*)p;            p += (size_t)NTOK * D_ * 4;   // 4MB f32
    u16* hbuf   = (u16*)p;              p += (size_t)NTOK * D_ * 2;   // 2MB
    u16* qbuf   = (u16*)p;              p += (size_t)NTOK * D_ * 2;
    u16* kbuf   = (u16*)p;              p += (size_t)NTOK * D_ * 2;
    u16* vbuf   = (u16*)p;              p += (size_t)NTOK * D_ * 2;
    u16* ybuf   = (u16*)p;              p += (size_t)NTOK * D_ * 2;
    u16* ff     = (u16*)p;              p += (size_t)NTOK * DF_ * 2;  // 8MB
    u16* WqT    = (u16*)p;              p += (size_t)L_ * D_ * D_ * 2;
    u16* WkT    = (u16*)p;              p += (size_t)L_ * D_ * D_ * 2;
    u16* WvT    = (u16*)p;              p += (size_t)L_ * D_ * D_ * 2;
    u16* WoT    = (u16*)p;              p += (size_t)L_ * D_ * D_ * 2;
    u16* W1T    = (u16*)p;              p += (size_t)L_ * D_ * DF_ * 2;
    u16* W2T    = (u16*)p;              p += (size_t)L_ * DF_ * D_ * 2;
    u16* hWT    = (u16*)p;              p += (size_t)V_ * D_ * 2;     // 16MB

    // weight prep (bf16 transposed)
    twb_kernel<<<dim3(8, 8, 4), 256, 0, stream>>>(Wq, WqT, D_, D_);
    twb_kernel<<<dim3(8, 8, 4), 256, 0, stream>>>(Wk, WkT, D_, D_);
    twb_kernel<<<dim3(8, 8, 4), 256, 0, stream>>>(Wv, WvT, D_, D_);
    twb_kernel<<<dim3(8, 8, 4), 256, 0, stream>>>(Wo, WoT, D_, D_);
    twb_kernel<<<dim3(32, 8, 4), 256, 0, stream>>>(W1, W1T, D_, DF_);
    twb_kernel<<<dim3(8, 32, 4), 256, 0, stream>>>(W2, W2T, DF_, D_);
    twb_kernel<<<dim3(1000, 8, 1), 256, 0, stream>>>(hW, hWT, D_, V_);

    embed_kernel<<<NTOK, 256, 0, stream>>>(idx, tok, pos, x);

    dim3 gProj(D_ / 128, NTOK / 128);    // (2, 32)
    dim3 gFF1(DF_ / 128, NTOK / 128);    // (8, 32)
    dim3 gHead(V_ / 128, NTOK / 128);    // (250, 32)
    dim3 gAttn(T_ / 64, B_ * H_);        // (32, 8)

    for (int l = 0; l < L_; l++) {
        ln_kernel<<<NTOK, 256, 0, stream>>>(x, ln1g + l * D_, ln1b + l * D_, hbuf);
        mfma_gemm<1><<<gProj, 256, 0, stream>>>(hbuf, WqT + (size_t)l * D_ * D_, bq + l * D_, nullptr, qbuf, NTOK, D_, D_);
        mfma_gemm<1><<<gProj, 256, 0, stream>>>(hbuf, WkT + (size_t)l * D_ * D_, bk + l * D_, nullptr, kbuf, NTOK, D_, D_);
        mfma_gemm<1><<<gProj, 256, 0, stream>>>(hbuf, WvT + (size_t)l * D_ * D_, bv + l * D_, nullptr, vbuf, NTOK, D_, D_);
        attn_kernel<<<gAttn, 256, 0, stream>>>(qbuf, kbuf, vbuf, ybuf);
        mfma_gemm<2><<<gProj, 256, 0, stream>>>(ybuf, WoT + (size_t)l * D_ * D_, bo + l * D_, x, x, NTOK, D_, D_);
        ln_kernel<<<NTOK, 256, 0, stream>>>(x, ln2g + l * D_, ln2b + l * D_, hbuf);
        mfma_gemm<3><<<gFF1, 256, 0, stream>>>(hbuf, W1T + (size_t)l * D_ * DF_, b1 + l * DF_, nullptr, ff, NTOK, DF_, D_);
        mfma_gemm<2><<<gProj, 256, 0, stream>>>(ff, W2T + (size_t)l * DF_ * D_, b2 + l * D_, x, x, NTOK, D_, DF_);
    }

    ln_kernel<<<NTOK, 256, 0, stream>>>(x, lnfg, lnfb, hbuf);
    mfma_gemm<0><<<gHead, 256, 0, stream>>>(hbuf, hWT, hb, nullptr, (float*)d_out, NTOK, V_, D_);
}

// Round 3
// 644.099 us; speedup vs baseline: 5.3297x; 1.2988x over previous
//
#include <hip/hip_runtime.h>
#include <hip/hip_bf16.h>
#include <math.h>

#define V_   32000
#define L_   4
#define H_   4
#define D_   256
#define DF_  1024
#define B_   2
#define T_   2048
#define DH_  64
#define NTOK (B_*T_)   // 4096

typedef __attribute__((ext_vector_type(8))) short bf16x8;
typedef __attribute__((ext_vector_type(4))) float f32x4;
typedef unsigned short u16;

#define GLOAD16(gsrc, ldst) \
  __builtin_amdgcn_global_load_lds((const __attribute__((address_space(1))) void*)(gsrc), \
                                   (__attribute__((address_space(3))) void*)(ldst), 16, 0, 0)

__device__ __forceinline__ u16 f2bf(float f) {
    unsigned int u = __builtin_bit_cast(unsigned int, f);
    u = (u + 0x7fff + ((u >> 16) & 1)) >> 16;   // RNE
    return (u16)u;
}

// ---------------- embedding ----------------
__global__ void embed_kernel(const int* __restrict__ idx, const float* __restrict__ tok,
                             const float* __restrict__ pos, float* __restrict__ x) {
    int n = blockIdx.x;
    int d = threadIdx.x;
    int t = n % T_;
    int id = idx[n];
    x[(size_t)n*D_ + d] = tok[(size_t)id*D_ + d] + pos[(size_t)t*D_ + d];
}

// ---------------- layernorm f32 -> bf16 ----------------
__global__ void ln_kernel(const float* __restrict__ x, const float* __restrict__ g,
                          const float* __restrict__ bta, u16* __restrict__ out) {
    int n = blockIdx.x;
    int d = threadIdx.x;
    float v = x[(size_t)n*D_ + d];
    __shared__ float red[4];
    float s = v;
    #pragma unroll
    for (int o = 32; o >= 1; o >>= 1) s += __shfl_xor(s, o);
    int wave = d >> 6, lane = d & 63;
    if (lane == 0) red[wave] = s;
    __syncthreads();
    float mu = (red[0] + red[1] + red[2] + red[3]) * (1.0f / D_);
    float c = v - mu;
    float s2 = c * c;
    #pragma unroll
    for (int o = 32; o >= 1; o >>= 1) s2 += __shfl_xor(s2, o);
    __syncthreads();
    if (lane == 0) red[wave] = s2;
    __syncthreads();
    float var = (red[0] + red[1] + red[2] + red[3]) * (1.0f / D_);
    out[(size_t)n*D_ + d] = f2bf(c * rsqrtf(var + 1e-5f) * g[d] + bta[d]);
}

// ---------------- generic weight transpose f32[K,N] -> bf16[N,K] ----------------
__global__ __launch_bounds__(256) void twb_kernel(const float* __restrict__ src,
                                                  u16* __restrict__ dst, int K, int N) {
    int z = blockIdx.z;
    src += (size_t)z * K * N;
    dst += (size_t)z * K * N;
    __shared__ float tile[32][33];
    int k0 = blockIdx.y * 32, n0 = blockIdx.x * 32;
    int tc = threadIdx.x & 31, tr = threadIdx.x >> 5;
    #pragma unroll
    for (int i = 0; i < 4; i++)
        tile[tr + i*8][tc] = src[(size_t)(k0 + tr + i*8) * N + n0 + tc];
    __syncthreads();
    #pragma unroll
    for (int i = 0; i < 4; i++)
        dst[(size_t)(n0 + tr + i*8) * K + k0 + tc] = f2bf(tile[tc][tr + i*8]);
}

// ---------------- fused transpose for the four 256x256 weight families ----------------
// z = wtype(0..3: q,k,v,o) | layer<<2.  q/k/v -> WqkvT [l][768][256], o -> WoT [l][256][256]
__global__ __launch_bounds__(256) void twb4_kernel(const float* __restrict__ Wq,
                                                   const float* __restrict__ Wk,
                                                   const float* __restrict__ Wv,
                                                   const float* __restrict__ Wo,
                                                   u16* __restrict__ WqkvT,
                                                   u16* __restrict__ WoT) {
    int z = blockIdx.z;
    int wt = z & 3, l = z >> 2;
    const float* src = (wt == 0 ? Wq : wt == 1 ? Wk : wt == 2 ? Wv : Wo) + (size_t)l * 65536;
    u16* dst = (wt < 3) ? (WqkvT + (size_t)l * 196608 + (size_t)wt * 65536)
                        : (WoT   + (size_t)l * 65536);
    __shared__ float tile[32][33];
    int k0 = blockIdx.y * 32, n0 = blockIdx.x * 32;
    int tc = threadIdx.x & 31, tr = threadIdx.x >> 5;
    #pragma unroll
    for (int i = 0; i < 4; i++)
        tile[tr + i*8][tc] = src[(size_t)(k0 + tr + i*8) * 256 + n0 + tc];
    __syncthreads();
    #pragma unroll
    for (int i = 0; i < 4; i++)
        dst[(size_t)(n0 + tr + i*8) * 256 + k0 + tc] = f2bf(tile[tc][tr + i*8]);
}

// ---------------- qkv bias concat: bqkv[l][768] ----------------
__global__ void concat_bias(const float* __restrict__ bq, const float* __restrict__ bk,
                            const float* __restrict__ bv, float* __restrict__ out) {
    int i = blockIdx.x * 256 + threadIdx.x;
    if (i >= L_ * 768) return;
    int l = i / 768, c = i % 768;
    int sel = c >> 8, cc = c & 255;
    const float* s = sel == 0 ? bq : sel == 1 ? bk : bv;
    out[i] = s[l * 256 + cc];
}

// ---------------- MFMA GEMM: C[M,N] = A[M,K](bf16) @ BT[N,K](bf16)^T + bias ----------------
// MODE 0: f32 out          MODE 1: bf16 qkv scatter (N=768, fused)
// MODE 2: f32 + residual   MODE 3: bf16 GELU
template<int BM, int BN, int MODE>
__global__ __launch_bounds__(256) void mfma_gemm(
    const u16* __restrict__ A, const u16* __restrict__ BT,
    const float* __restrict__ bias, const float* res,
    void* Cout, int M, int N, int K)
{
    constexpr int FM = BM / 32, FN = BN / 32;       // 16x16 frags per wave
    constexpr int ACH = BM / 32, BCH = BN / 32;     // 16B chunks per thread per tile
    __shared__ u16 As[BM * 64];
    __shared__ u16 Bs[BN * 64];
    int tid = threadIdx.x;
    int lane = tid & 63, w = tid >> 6;
    int lr = lane & 15, lg = lane >> 4;
    int wm = w >> 1, wn = w & 1;

    int gx = gridDim.x;
    int nwg = gx * gridDim.y;
    int orig = blockIdx.y * gx + blockIdx.x;
    int bid = ((nwg & 7) == 0) ? ((orig & 7) * (nwg >> 3) + (orig >> 3)) : orig;
    int row0 = (bid / gx) * BM, col0 = (bid % gx) * BN;

    f32x4 acc[FM][FN] = {};

    for (int k0 = 0; k0 < K; k0 += 64) {
        __syncthreads();
        #pragma unroll
        for (int i = 0; i < ACH; i++) {
            int o16 = tid + i * 256;
            int r = o16 >> 3;
            int sw = ((o16 & 7) << 4) ^ ((r & 7) << 4);
            GLOAD16(A + (size_t)(row0 + r) * K + k0 + (sw >> 1), &As[o16 * 8]);
        }
        #pragma unroll
        for (int i = 0; i < BCH; i++) {
            int o16 = tid + i * 256;
            int r = o16 >> 3;
            int sw = ((o16 & 7) << 4) ^ ((r & 7) << 4);
            GLOAD16(BT + (size_t)(col0 + r) * K + k0 + (sw >> 1), &Bs[o16 * 8]);
        }
        __syncthreads();
        #pragma unroll
        for (int ks = 0; ks < 2; ks++) {
            bf16x8 af[FM], bfr[FN];
            #pragma unroll
            for (int mi = 0; mi < FM; mi++) {
                int rr = wm * (BM / 2) + mi * 16 + lr;
                af[mi] = *(const bf16x8*)(As + rr * 64 + (((ks * 64 + lg * 16) ^ ((rr & 7) << 4)) >> 1));
            }
            #pragma unroll
            for (int ni = 0; ni < FN; ni++) {
                int rr = wn * (BN / 2) + ni * 16 + lr;
                bfr[ni] = *(const bf16x8*)(Bs + rr * 64 + (((ks * 64 + lg * 16) ^ ((rr & 7) << 4)) >> 1));
            }
            #pragma unroll
            for (int mi = 0; mi < FM; mi++)
                #pragma unroll
                for (int ni = 0; ni < FN; ni++)
                    acc[mi][ni] = __builtin_amdgcn_mfma_f32_16x16x32_bf16(af[mi], bfr[ni], acc[mi][ni], 0, 0, 0);
        }
    }

    #pragma unroll
    for (int mi = 0; mi < FM; mi++) {
        #pragma unroll
        for (int ni = 0; ni < FN; ni++) {
            #pragma unroll
            for (int j = 0; j < 4; j++) {
                int row = row0 + wm * (BM / 2) + mi * 16 + lg * 4 + j;
                int col = col0 + wn * (BN / 2) + ni * 16 + lr;
                float v = acc[mi][ni][j] + bias[col];
                if (MODE == 0) {
                    ((float*)Cout)[(size_t)row * N + col] = v;
                } else if (MODE == 2) {
                    ((float*)Cout)[(size_t)row * N + col] = v + res[(size_t)row * N + col];
                } else if (MODE == 3) {
                    v = 0.5f * v * (1.0f + erff(v * 0.70710678118f));
                    ((u16*)Cout)[(size_t)row * N + col] = f2bf(v);
                } else {   // MODE 1: fused qkv scatter to 3x [B,H,T,DH]
                    int qsel = col >> 8, c = col & 255;
                    int bb = row >> 11, t = row & (T_ - 1);
                    int h = c >> 6, dh = c & 63;
                    ((u16*)Cout)[(size_t)qsel * NTOK * D_ +
                                 ((((size_t)bb * H_ + h) * T_) + t) * DH_ + dh] = f2bf(v);
                }
            }
        }
    }
}

// ---------------- MFMA causal flash attention ----------------
__global__ __launch_bounds__(256) void attn_kernel(
    const u16* __restrict__ q, const u16* __restrict__ k,
    const u16* __restrict__ v, u16* __restrict__ y)
{
    int qb = blockIdx.x;
    int bh = blockIdx.y;
    int bidx = bh >> 2, h = bh & 3;
    const u16* qp = q + (size_t)bh * T_ * DH_;
    const u16* kp = k + (size_t)bh * T_ * DH_;
    const u16* vp = v + (size_t)bh * T_ * DH_;

    __shared__ u16 Qs[64*64];
    __shared__ u16 Ks[64*64];
    __shared__ u16 VT[64*72];
    __shared__ u16 Ps[4][16*72];

    int tid = threadIdx.x;
    int lane = tid & 63, w = tid >> 6;
    int lr = lane & 15, lg = lane >> 4;

    #pragma unroll
    for (int i = 0; i < 2; i++) {
        int o16 = tid + i * 256;
        int r = o16 >> 3;
        int sw = ((o16 & 7) << 4) ^ ((r & 7) << 4);
        GLOAD16(qp + (size_t)(qb * 64 + r) * DH_ + (sw >> 1), &Qs[o16 * 8]);
    }
    int vkey = tid & 63;
    int vdh0 = (tid >> 6) * 8;
    __syncthreads();

    bf16x8 qa[2];
    #pragma unroll
    for (int ks = 0; ks < 2; ks++) {
        int rr = w * 16 + lr;
        qa[ks] = *(const bf16x8*)(Qs + rr * 64 + (((ks * 64 + lg * 16) ^ ((rr & 7) << 4)) >> 1));
    }

    float m[4], lden[4];
    f32x4 o[4] = {};
    #pragma unroll
    for (int j = 0; j < 4; j++) { m[j] = -1e30f; lden[j] = 0.0f; }

    for (int kc = 0; kc <= qb; kc++) {
        __syncthreads();
        #pragma unroll
        for (int i = 0; i < 2; i++) {
            int o16 = tid + i * 256;
            int r = o16 >> 3;
            int sw = ((o16 & 7) << 4) ^ ((r & 7) << 4);
            GLOAD16(kp + (size_t)(kc * 64 + r) * DH_ + (sw >> 1), &Ks[o16 * 8]);
        }
        #pragma unroll
        for (int half = 0; half < 2; half++) {
            int dh0 = vdh0 + half * 32;
            bf16x8 vv = *(const bf16x8*)(vp + (size_t)(kc * 64 + vkey) * DH_ + dh0);
            #pragma unroll
            for (int e = 0; e < 8; e++)
                VT[(dh0 + e) * 72 + vkey] = (u16)vv[e];
        }
        __syncthreads();

        f32x4 sc[4];
        #pragma unroll
        for (int ct = 0; ct < 4; ct++) {
            f32x4 s = {};
            #pragma unroll
            for (int ks = 0; ks < 2; ks++) {
                int rr = ct * 16 + lr;
                bf16x8 kb = *(const bf16x8*)(Ks + rr * 64 + (((ks * 64 + lg * 16) ^ ((rr & 7) << 4)) >> 1));
                s = __builtin_amdgcn_mfma_f32_16x16x32_bf16(qa[ks], kb, s, 0, 0, 0);
            }
            sc[ct] = s;
        }
        float mloc[4];
        #pragma unroll
        for (int j = 0; j < 4; j++) mloc[j] = -1e30f;
        #pragma unroll
        for (int ct = 0; ct < 4; ct++)
            #pragma unroll
            for (int j = 0; j < 4; j++) {
                float s = sc[ct][j] * 0.125f;
                if (kc == qb && (ct * 16 + lr) > (w * 16 + lg * 4 + j)) s = -1e30f;
                sc[ct][j] = s;
                mloc[j] = fmaxf(mloc[j], s);
            }
        #pragma unroll
        for (int j = 0; j < 4; j++) {
            mloc[j] = fmaxf(mloc[j], __shfl_xor(mloc[j], 1));
            mloc[j] = fmaxf(mloc[j], __shfl_xor(mloc[j], 2));
            mloc[j] = fmaxf(mloc[j], __shfl_xor(mloc[j], 4));
            mloc[j] = fmaxf(mloc[j], __shfl_xor(mloc[j], 8));
        }
        float f[4], rs[4];
        #pragma unroll
        for (int j = 0; j < 4; j++) {
            float nm = fmaxf(m[j], mloc[j]);
            f[j] = __expf(m[j] - nm);
            m[j] = nm;
            rs[j] = 0.0f;
        }
        #pragma unroll
        for (int ct = 0; ct < 4; ct++)
            #pragma unroll
            for (int j = 0; j < 4; j++) {
                float p = __expf(sc[ct][j] - m[j]);
                rs[j] += p;
                Ps[w][(lg * 4 + j) * 72 + ct * 16 + lr] = f2bf(p);
            }
        #pragma unroll
        for (int j = 0; j < 4; j++) {
            rs[j] += __shfl_xor(rs[j], 1);
            rs[j] += __shfl_xor(rs[j], 2);
            rs[j] += __shfl_xor(rs[j], 4);
            rs[j] += __shfl_xor(rs[j], 8);
            lden[j] = lden[j] * f[j] + rs[j];
        }
        #pragma unroll
        for (int dt = 0; dt < 4; dt++)
            #pragma unroll
            for (int j = 0; j < 4; j++)
                o[dt][j] *= f[j];
        #pragma unroll
        for (int ks = 0; ks < 2; ks++) {
            bf16x8 pa = *(const bf16x8*)(&Ps[w][lr * 72 + ks * 32 + lg * 8]);
            #pragma unroll
            for (int dt = 0; dt < 4; dt++) {
                bf16x8 vb = *(const bf16x8*)(&VT[(dt * 16 + lr) * 72 + ks * 32 + lg * 8]);
                o[dt] = __builtin_amdgcn_mfma_f32_16x16x32_bf16(pa, vb, o[dt], 0, 0, 0);
            }
        }
    }

    #pragma unroll
    for (int j = 0; j < 4; j++) {
        float inv = 1.0f / lden[j];
        int q_g = qb * 64 + w * 16 + lg * 4 + j;
        size_t base = ((size_t)(bidx * T_ + q_g)) * D_ + h * DH_;
        #pragma unroll
        for (int dt = 0; dt < 4; dt++)
            y[base + dt * 16 + lr] = f2bf(o[dt][j] * inv);
    }
}

// ---------------- host launch ----------------
extern "C" void kernel_launch(void* const* d_in, const int* in_sizes, int n_in,
                              void* d_out, int out_size, void* d_ws, size_t ws_size,
                              hipStream_t stream)
{
    const int*   idx  = (const int*)d_in[0];
    const float* tok  = (const float*)d_in[1];
    const float* pos  = (const float*)d_in[2];
    const float* Wq   = (const float*)d_in[3];
    const float* bq   = (const float*)d_in[4];
    const float* Wk   = (const float*)d_in[5];
    const float* bk   = (const float*)d_in[6];
    const float* Wv   = (const float*)d_in[7];
    const float* bv   = (const float*)d_in[8];
    const float* Wo   = (const float*)d_in[9];
    const float* bo   = (const float*)d_in[10];
    const float* ln1g = (const float*)d_in[11];
    const float* ln1b = (const float*)d_in[12];
    const float* W1   = (const float*)d_in[13];
    const float* b1   = (const float*)d_in[14];
    const float* W2   = (const float*)d_in[15];
    const float* b2   = (const float*)d_in[16];
    const float* ln2g = (const float*)d_in[17];
    const float* ln2b = (const float*)d_in[18];
    const float* lnfg = (const float*)d_in[19];
    const float* lnfb = (const float*)d_in[20];
    const float* hW   = (const float*)d_in[21];
    const float* hb   = (const float*)d_in[22];

    char* p = (char*)d_ws;
    float* x     = (float*)p;           p += (size_t)NTOK * D_ * 4;
    u16* hbuf    = (u16*)p;             p += (size_t)NTOK * D_ * 2;
    u16* qbuf    = (u16*)p;             p += (size_t)NTOK * D_ * 2;   // q,k,v contiguous!
    u16* kbuf    = (u16*)p;             p += (size_t)NTOK * D_ * 2;
    u16* vbuf    = (u16*)p;             p += (size_t)NTOK * D_ * 2;
    u16* ybuf    = (u16*)p;             p += (size_t)NTOK * D_ * 2;
    u16* ff      = (u16*)p;             p += (size_t)NTOK * DF_ * 2;
    u16* WqkvT   = (u16*)p;             p += (size_t)L_ * 768 * D_ * 2;
    u16* WoT     = (u16*)p;             p += (size_t)L_ * D_ * D_ * 2;
    u16* W1T     = (u16*)p;             p += (size_t)L_ * D_ * DF_ * 2;
    u16* W2T     = (u16*)p;             p += (size_t)L_ * DF_ * D_ * 2;
    u16* hWT     = (u16*)p;             p += (size_t)V_ * D_ * 2;
    float* bqkv  = (float*)p;           p += (size_t)L_ * 768 * 4;

    // weight prep
    twb4_kernel<<<dim3(8, 8, 16), 256, 0, stream>>>(Wq, Wk, Wv, Wo, WqkvT, WoT);
    twb_kernel<<<dim3(32, 8, 4), 256, 0, stream>>>(W1, W1T, D_, DF_);
    twb_kernel<<<dim3(8, 32, 4), 256, 0, stream>>>(W2, W2T, DF_, D_);
    twb_kernel<<<dim3(1000, 8, 1), 256, 0, stream>>>(hW, hWT, D_, V_);
    concat_bias<<<12, 256, 0, stream>>>(bq, bk, bv, bqkv);

    embed_kernel<<<NTOK, 256, 0, stream>>>(idx, tok, pos, x);

    dim3 gQkv(768 / 64, NTOK / 64);      // (12, 64)
    dim3 gWo(D_ / 64, NTOK / 64);        // (4, 64)
    dim3 gFF1(DF_ / 64, NTOK / 64);      // (16, 64)
    dim3 gHead(V_ / 128, NTOK / 128);    // (250, 32)
    dim3 gAttn(T_ / 64, B_ * H_);        // (32, 8)

    for (int l = 0; l < L_; l++) {
        ln_kernel<<<NTOK, 256, 0, stream>>>(x, ln1g + l * D_, ln1b + l * D_, hbuf);
        mfma_gemm<64, 64, 1><<<gQkv, 256, 0, stream>>>(hbuf, WqkvT + (size_t)l * 768 * D_, bqkv + l * 768, nullptr, qbuf, NTOK, 768, D_);
        attn_kernel<<<gAttn, 256, 0, stream>>>(qbuf, kbuf, vbuf, ybuf);
        mfma_gemm<64, 64, 2><<<gWo, 256, 0, stream>>>(ybuf, WoT + (size_t)l * D_ * D_, bo + l * D_, x, x, NTOK, D_, D_);
        ln_kernel<<<NTOK, 256, 0, stream>>>(x, ln2g + l * D_, ln2b + l * D_, hbuf);
        mfma_gemm<64, 64, 3><<<gFF1, 256, 0, stream>>>(hbuf, W1T + (size_t)l * D_ * DF_, b1 + l * DF_, nullptr, ff, NTOK, DF_, D_);
        mfma_gemm<64, 64, 2><<<gWo, 256, 0, stream>>>(ff, W2T + (size_t)l * DF_ * D_, b2 + l * D_, x, x, NTOK, D_, DF_);
    }

    ln_kernel<<<NTOK, 256, 0, stream>>>(x, lnfg, lnfb, hbuf);
    mfma_gemm<128, 128, 0><<<gHead, 256, 0, stream>>>(hbuf, hWT, hb, nullptr, (float*)d_out, NTOK, V_, D_);
}

// Round 4
// 594.878 us; speedup vs baseline: 5.7707x; 1.0827x over previous
//
#include <hip/hip_runtime.h>
#include <hip/hip_bf16.h>
#include <math.h>

#define V_   32000
#define L_   4
#define H_   4
#define D_   256
#define DF_  1024
#define B_   2
#define T_   2048
#define DH_  64
#define NTOK (B_*T_)   // 4096

typedef __attribute__((ext_vector_type(8))) short bf16x8;
typedef __attribute__((ext_vector_type(4))) float f32x4;
typedef unsigned short u16;

#define GLOAD16(gsrc, ldst) \
  __builtin_amdgcn_global_load_lds((const __attribute__((address_space(1))) void*)(gsrc), \
                                   (__attribute__((address_space(3))) void*)(ldst), 16, 0, 0)

__device__ __forceinline__ u16 f2bf(float f) {
    unsigned int u = __builtin_bit_cast(unsigned int, f);
    u = (u + 0x7fff + ((u >> 16) & 1)) >> 16;   // RNE
    return (u16)u;
}

// ---------------- embed + ln1(layer0): writes x (f32) and h (bf16) ----------------
__global__ void embed_ln_kernel(const int* __restrict__ idx, const float* __restrict__ tok,
                                const float* __restrict__ pos, const float* __restrict__ g,
                                const float* __restrict__ bta, float* __restrict__ x,
                                u16* __restrict__ h) {
    int n = blockIdx.x;
    int d = threadIdx.x;
    int t = n % T_;
    int id = idx[n];
    float v = tok[(size_t)id*D_ + d] + pos[(size_t)t*D_ + d];
    x[(size_t)n*D_ + d] = v;
    __shared__ float red[4];
    float s = v;
    #pragma unroll
    for (int o = 32; o >= 1; o >>= 1) s += __shfl_xor(s, o);
    int wave = d >> 6, lane = d & 63;
    if (lane == 0) red[wave] = s;
    __syncthreads();
    float mu = (red[0] + red[1] + red[2] + red[3]) * (1.0f / D_);
    float c = v - mu;
    float s2 = c * c;
    #pragma unroll
    for (int o = 32; o >= 1; o >>= 1) s2 += __shfl_xor(s2, o);
    __syncthreads();
    if (lane == 0) red[wave] = s2;
    __syncthreads();
    float var = (red[0] + red[1] + red[2] + red[3]) * (1.0f / D_);
    h[(size_t)n*D_ + d] = f2bf(c * rsqrtf(var + 1e-5f) * g[d] + bta[d]);
}

// ---------------- generic weight transpose f32[K,N] -> bf16[N,K] ----------------
__global__ __launch_bounds__(256) void twb_kernel(const float* __restrict__ src,
                                                  u16* __restrict__ dst, int K, int N) {
    int z = blockIdx.z;
    src += (size_t)z * K * N;
    dst += (size_t)z * K * N;
    __shared__ float tile[32][33];
    int k0 = blockIdx.y * 32, n0 = blockIdx.x * 32;
    int tc = threadIdx.x & 31, tr = threadIdx.x >> 5;
    #pragma unroll
    for (int i = 0; i < 4; i++)
        tile[tr + i*8][tc] = src[(size_t)(k0 + tr + i*8) * N + n0 + tc];
    __syncthreads();
    #pragma unroll
    for (int i = 0; i < 4; i++)
        dst[(size_t)(n0 + tr + i*8) * K + k0 + tc] = f2bf(tile[tc][tr + i*8]);
}

// ---------------- fused transpose for the four 256x256 weight families ----------------
__global__ __launch_bounds__(256) void twb4_kernel(const float* __restrict__ Wq,
                                                   const float* __restrict__ Wk,
                                                   const float* __restrict__ Wv,
                                                   const float* __restrict__ Wo,
                                                   u16* __restrict__ WqkvT,
                                                   u16* __restrict__ WoT) {
    int z = blockIdx.z;
    int wt = z & 3, l = z >> 2;
    const float* src = (wt == 0 ? Wq : wt == 1 ? Wk : wt == 2 ? Wv : Wo) + (size_t)l * 65536;
    u16* dst = (wt < 3) ? (WqkvT + (size_t)l * 196608 + (size_t)wt * 65536)
                        : (WoT   + (size_t)l * 65536);
    __shared__ float tile[32][33];
    int k0 = blockIdx.y * 32, n0 = blockIdx.x * 32;
    int tc = threadIdx.x & 31, tr = threadIdx.x >> 5;
    #pragma unroll
    for (int i = 0; i < 4; i++)
        tile[tr + i*8][tc] = src[(size_t)(k0 + tr + i*8) * 256 + n0 + tc];
    __syncthreads();
    #pragma unroll
    for (int i = 0; i < 4; i++)
        dst[(size_t)(n0 + tr + i*8) * 256 + k0 + tc] = f2bf(tile[tc][tr + i*8]);
}

// ---------------- MFMA GEMM, double-buffered ----------------
// MODE 0: f32 out (head)      MODE 1: bf16 qkv scatter, 3-way bias (N=768)
// MODE 3: bf16 GELU           MODE 4: residual + f32 x-out + LayerNorm -> bf16 h-out (BN==N==256)
template<int BM, int BN, int MODE>
__global__ __launch_bounds__(256) void mfma_gemm(
    const u16* __restrict__ A, const u16* __restrict__ BT,
    const float* __restrict__ b0, const float* __restrict__ b1, const float* __restrict__ b2,
    const float* __restrict__ lng, const float* __restrict__ lnb,
    const float* res, void* Cout, u16* Cout2,
    int M, int N, int K)
{
    constexpr int FM = BM / 32, FN = BN / 32;
    constexpr int ACH = (BM * 64 * 2) / (16 * 256);
    constexpr int BCH = (BN * 64 * 2) / (16 * 256);
    static_assert(MODE != 4 || FM == 1, "MODE4 requires BM==32");
    __shared__ u16 As[2][BM * 64];
    __shared__ u16 Bs[2][BN * 64];
    __shared__ float sred[2][2][16], qred[2][2][16];

    int tid = threadIdx.x;
    int lane = tid & 63, w = tid >> 6;
    int lr = lane & 15, lg = lane >> 4;
    int wm = w >> 1, wn = w & 1;

    int gx = gridDim.x;
    int nwg = gx * gridDim.y;
    int orig = blockIdx.y * gx + blockIdx.x;
    int bid = ((nwg & 7) == 0) ? ((orig & 7) * (nwg >> 3) + (orig >> 3)) : orig;
    int row0 = (bid / gx) * BM, col0 = (bid % gx) * BN;

    f32x4 acc[FM][FN] = {};

    auto stage = [&](int buf, int k0) {
        #pragma unroll
        for (int i = 0; i < ACH; i++) {
            int o16 = tid + i * 256;
            int r = o16 >> 3;
            int sw = ((o16 & 7) << 4) ^ ((r & 7) << 4);
            GLOAD16(A + (size_t)(row0 + r) * K + k0 + (sw >> 1), &As[buf][o16 * 8]);
        }
        #pragma unroll
        for (int i = 0; i < BCH; i++) {
            int o16 = tid + i * 256;
            int r = o16 >> 3;
            int sw = ((o16 & 7) << 4) ^ ((r & 7) << 4);
            GLOAD16(BT + (size_t)(col0 + r) * K + k0 + (sw >> 1), &Bs[buf][o16 * 8]);
        }
    };

    stage(0, 0);
    int nk = K >> 6;
    for (int t = 0; t < nk; t++) {
        int cur = t & 1;
        __syncthreads();                       // drains vmcnt -> buf[cur] ready
        if (t + 1 < nk) stage(cur ^ 1, (t + 1) << 6);
        #pragma unroll
        for (int ks = 0; ks < 2; ks++) {
            bf16x8 af[FM], bfr[FN];
            #pragma unroll
            for (int mi = 0; mi < FM; mi++) {
                int rr = wm * (BM / 2) + mi * 16 + lr;
                af[mi] = *(const bf16x8*)(&As[cur][rr * 64 + (((ks * 64 + lg * 16) ^ ((rr & 7) << 4)) >> 1)]);
            }
            #pragma unroll
            for (int ni = 0; ni < FN; ni++) {
                int rr = wn * (BN / 2) + ni * 16 + lr;
                bfr[ni] = *(const bf16x8*)(&Bs[cur][rr * 64 + (((ks * 64 + lg * 16) ^ ((rr & 7) << 4)) >> 1)]);
            }
            __builtin_amdgcn_s_setprio(1);
            #pragma unroll
            for (int mi = 0; mi < FM; mi++)
                #pragma unroll
                for (int ni = 0; ni < FN; ni++)
                    acc[mi][ni] = __builtin_amdgcn_mfma_f32_16x16x32_bf16(af[mi], bfr[ni], acc[mi][ni], 0, 0, 0);
            __builtin_amdgcn_s_setprio(0);
        }
    }

    if constexpr (MODE == 4) {
        float vals[FN][4];
        float rs[4] = {0.f, 0.f, 0.f, 0.f}, rq[4] = {0.f, 0.f, 0.f, 0.f};
        #pragma unroll
        for (int ni = 0; ni < FN; ni++) {
            #pragma unroll
            for (int j = 0; j < 4; j++) {
                int row = row0 + wm * 16 + lg * 4 + j;
                int col = wn * (BN / 2) + ni * 16 + lr;
                float v = acc[0][ni][j] + b0[col] + ((const float*)res)[(size_t)row * N + col];
                ((float*)Cout)[(size_t)row * N + col] = v;
                vals[ni][j] = v;
                rs[j] += v;
                rq[j] += v * v;
            }
        }
        #pragma unroll
        for (int j = 0; j < 4; j++) {
            #pragma unroll
            for (int o = 1; o <= 8; o <<= 1) {
                rs[j] += __shfl_xor(rs[j], o);
                rq[j] += __shfl_xor(rq[j], o);
            }
        }
        if (lr == 0) {
            #pragma unroll
            for (int j = 0; j < 4; j++) {
                sred[wm][wn][lg * 4 + j] = rs[j];
                qred[wm][wn][lg * 4 + j] = rq[j];
            }
        }
        __syncthreads();
        #pragma unroll
        for (int j = 0; j < 4; j++) {
            int r16 = lg * 4 + j;
            int row = row0 + wm * 16 + r16;
            float mu = (sred[wm][0][r16] + sred[wm][1][r16]) * (1.0f / 256.0f);
            float var = (qred[wm][0][r16] + qred[wm][1][r16]) * (1.0f / 256.0f) - mu * mu;
            float ri = rsqrtf(var + 1e-5f);
            #pragma unroll
            for (int ni = 0; ni < FN; ni++) {
                int col = wn * (BN / 2) + ni * 16 + lr;
                Cout2[(size_t)row * N + col] = f2bf((vals[ni][j] - mu) * ri * lng[col] + lnb[col]);
            }
        }
    } else {
        #pragma unroll
        for (int mi = 0; mi < FM; mi++) {
            #pragma unroll
            for (int ni = 0; ni < FN; ni++) {
                #pragma unroll
                for (int j = 0; j < 4; j++) {
                    int row = row0 + wm * (BM / 2) + mi * 16 + lg * 4 + j;
                    int col = col0 + wn * (BN / 2) + ni * 16 + lr;
                    if (MODE == 0) {
                        ((float*)Cout)[(size_t)row * N + col] = acc[mi][ni][j] + b0[col];
                    } else if (MODE == 3) {
                        float v = acc[mi][ni][j] + b0[col];
                        v = 0.5f * v * (1.0f + erff(v * 0.70710678118f));
                        Cout2[(size_t)row * N + col] = f2bf(v);
                    } else {   // MODE 1
                        int sel = col >> 8, c = col & 255;
                        const float* bp = sel == 0 ? b0 : sel == 1 ? b1 : b2;
                        float v = acc[mi][ni][j] + bp[c];
                        int bb = row >> 11, t = row & (T_ - 1);
                        int h = c >> 6, dh = c & 63;
                        Cout2[(size_t)sel * NTOK * D_ +
                              ((((size_t)bb * H_ + h) * T_) + t) * DH_ + dh] = f2bf(v);
                    }
                }
            }
        }
    }
}

// ---------------- MFMA causal flash attention, software-pipelined ----------------
__global__ __launch_bounds__(256) void attn_kernel(
    const u16* __restrict__ q, const u16* __restrict__ k,
    const u16* __restrict__ v, u16* __restrict__ y)
{
    int qb = blockIdx.x;
    int bh = blockIdx.y;
    int bidx = bh >> 2, h = bh & 3;
    const u16* qp = q + (size_t)bh * T_ * DH_;
    const u16* kp = k + (size_t)bh * T_ * DH_;
    const u16* vp = v + (size_t)bh * T_ * DH_;

    __shared__ u16 Qs[64*64];
    __shared__ u16 Ks[2][64*64];
    __shared__ u16 VT[2][64*72];
    __shared__ u16 Ps[4][16*72];

    int tid = threadIdx.x;
    int lane = tid & 63, w = tid >> 6;
    int lr = lane & 15, lg = lane >> 4;
    int vkey = tid & 63;
    int vdh0 = (tid >> 6) * 8;

    // stage Q + K0 + V0
    #pragma unroll
    for (int i = 0; i < 2; i++) {
        int o16 = tid + i * 256;
        int r = o16 >> 3;
        int sw = ((o16 & 7) << 4) ^ ((r & 7) << 4);
        GLOAD16(qp + (size_t)(qb * 64 + r) * DH_ + (sw >> 1), &Qs[o16 * 8]);
        GLOAD16(kp + (size_t)r * DH_ + (sw >> 1), &Ks[0][o16 * 8]);
    }
    bf16x8 vva = *(const bf16x8*)(vp + (size_t)vkey * DH_ + vdh0);
    bf16x8 vvb = *(const bf16x8*)(vp + (size_t)vkey * DH_ + vdh0 + 32);
    __syncthreads();
    #pragma unroll
    for (int e = 0; e < 8; e++) {
        VT[0][(vdh0 + e) * 72 + vkey] = (u16)vva[e];
        VT[0][(vdh0 + 32 + e) * 72 + vkey] = (u16)vvb[e];
    }
    bf16x8 qa[2];
    #pragma unroll
    for (int ks = 0; ks < 2; ks++) {
        int rr = w * 16 + lr;
        qa[ks] = *(const bf16x8*)(Qs + rr * 64 + (((ks * 64 + lg * 16) ^ ((rr & 7) << 4)) >> 1));
    }
    __syncthreads();

    float m[4], lden[4];
    f32x4 o[4] = {};
    #pragma unroll
    for (int j = 0; j < 4; j++) { m[j] = -1e30f; lden[j] = 0.0f; }

    for (int kc = 0; kc <= qb; kc++) {
        int cur = kc & 1, nxt = cur ^ 1;
        bf16x8 nva, nvb;
        if (kc < qb) {   // prefetch K(kc+1), V(kc+1)
            #pragma unroll
            for (int i = 0; i < 2; i++) {
                int o16 = tid + i * 256;
                int r = o16 >> 3;
                int sw = ((o16 & 7) << 4) ^ ((r & 7) << 4);
                GLOAD16(kp + (size_t)((kc + 1) * 64 + r) * DH_ + (sw >> 1), &Ks[nxt][o16 * 8]);
            }
            nva = *(const bf16x8*)(vp + (size_t)((kc + 1) * 64 + vkey) * DH_ + vdh0);
            nvb = *(const bf16x8*)(vp + (size_t)((kc + 1) * 64 + vkey) * DH_ + vdh0 + 32);
        }

        f32x4 sc[4];
        #pragma unroll
        for (int ct = 0; ct < 4; ct++) {
            f32x4 s = {};
            __builtin_amdgcn_s_setprio(1);
            #pragma unroll
            for (int ks = 0; ks < 2; ks++) {
                int rr = ct * 16 + lr;
                bf16x8 kb = *(const bf16x8*)(&Ks[cur][rr * 64 + (((ks * 64 + lg * 16) ^ ((rr & 7) << 4)) >> 1)]);
                s = __builtin_amdgcn_mfma_f32_16x16x32_bf16(qa[ks], kb, s, 0, 0, 0);
            }
            __builtin_amdgcn_s_setprio(0);
            sc[ct] = s;
        }
        float mloc[4];
        #pragma unroll
        for (int j = 0; j < 4; j++) mloc[j] = -1e30f;
        #pragma unroll
        for (int ct = 0; ct < 4; ct++)
            #pragma unroll
            for (int j = 0; j < 4; j++) {
                float s = sc[ct][j] * 0.125f;
                if (kc == qb && (ct * 16 + lr) > (w * 16 + lg * 4 + j)) s = -1e30f;
                sc[ct][j] = s;
                mloc[j] = fmaxf(mloc[j], s);
            }
        #pragma unroll
        for (int j = 0; j < 4; j++) {
            mloc[j] = fmaxf(mloc[j], __shfl_xor(mloc[j], 1));
            mloc[j] = fmaxf(mloc[j], __shfl_xor(mloc[j], 2));
            mloc[j] = fmaxf(mloc[j], __shfl_xor(mloc[j], 4));
            mloc[j] = fmaxf(mloc[j], __shfl_xor(mloc[j], 8));
        }
        float f[4], rs[4];
        #pragma unroll
        for (int j = 0; j < 4; j++) {
            float nm = fmaxf(m[j], mloc[j]);
            f[j] = __expf(m[j] - nm);
            m[j] = nm;
            rs[j] = 0.0f;
        }
        #pragma unroll
        for (int ct = 0; ct < 4; ct++)
            #pragma unroll
            for (int j = 0; j < 4; j++) {
                float p = __expf(sc[ct][j] - m[j]);
                rs[j] += p;
                Ps[w][(lg * 4 + j) * 72 + ct * 16 + lr] = f2bf(p);
            }
        #pragma unroll
        for (int j = 0; j < 4; j++) {
            rs[j] += __shfl_xor(rs[j], 1);
            rs[j] += __shfl_xor(rs[j], 2);
            rs[j] += __shfl_xor(rs[j], 4);
            rs[j] += __shfl_xor(rs[j], 8);
            lden[j] = lden[j] * f[j] + rs[j];
        }
        #pragma unroll
        for (int dt = 0; dt < 4; dt++)
            #pragma unroll
            for (int j = 0; j < 4; j++)
                o[dt][j] *= f[j];
        #pragma unroll
        for (int ks = 0; ks < 2; ks++) {
            bf16x8 pa = *(const bf16x8*)(&Ps[w][lr * 72 + ks * 32 + lg * 8]);
            __builtin_amdgcn_s_setprio(1);
            #pragma unroll
            for (int dt = 0; dt < 4; dt++) {
                bf16x8 vb = *(const bf16x8*)(&VT[cur][(dt * 16 + lr) * 72 + ks * 32 + lg * 8]);
                o[dt] = __builtin_amdgcn_mfma_f32_16x16x32_bf16(pa, vb, o[dt], 0, 0, 0);
            }
            __builtin_amdgcn_s_setprio(0);
        }
        if (kc < qb) {
            #pragma unroll
            for (int e = 0; e < 8; e++) {
                VT[nxt][(vdh0 + e) * 72 + vkey] = (u16)nva[e];
                VT[nxt][(vdh0 + 32 + e) * 72 + vkey] = (u16)nvb[e];
            }
        }
        __syncthreads();
    }

    #pragma unroll
    for (int j = 0; j < 4; j++) {
        float inv = 1.0f / lden[j];
        int q_g = qb * 64 + w * 16 + lg * 4 + j;
        size_t base = ((size_t)(bidx * T_ + q_g)) * D_ + h * DH_;
        #pragma unroll
        for (int dt = 0; dt < 4; dt++)
            y[base + dt * 16 + lr] = f2bf(o[dt][j] * inv);
    }
}

// ---------------- host launch ----------------
extern "C" void kernel_launch(void* const* d_in, const int* in_sizes, int n_in,
                              void* d_out, int out_size, void* d_ws, size_t ws_size,
                              hipStream_t stream)
{
    const int*   idx  = (const int*)d_in[0];
    const float* tok  = (const float*)d_in[1];
    const float* pos  = (const float*)d_in[2];
    const float* Wq   = (const float*)d_in[3];
    const float* bq   = (const float*)d_in[4];
    const float* Wk   = (const float*)d_in[5];
    const float* bk   = (const float*)d_in[6];
    const float* Wv   = (const float*)d_in[7];
    const float* bv   = (const float*)d_in[8];
    const float* Wo   = (const float*)d_in[9];
    const float* bo   = (const float*)d_in[10];
    const float* ln1g = (const float*)d_in[11];
    const float* ln1b = (const float*)d_in[12];
    const float* W1   = (const float*)d_in[13];
    const float* b1   = (const float*)d_in[14];
    const float* W2   = (const float*)d_in[15];
    const float* b2   = (const float*)d_in[16];
    const float* ln2g = (const float*)d_in[17];
    const float* ln2b = (const float*)d_in[18];
    const float* lnfg = (const float*)d_in[19];
    const float* lnfb = (const float*)d_in[20];
    const float* hW   = (const float*)d_in[21];
    const float* hb   = (const float*)d_in[22];

    char* p = (char*)d_ws;
    float* x     = (float*)p;           p += (size_t)NTOK * D_ * 4;
    u16* hbuf    = (u16*)p;             p += (size_t)NTOK * D_ * 2;
    u16* qbuf    = (u16*)p;             p += (size_t)NTOK * D_ * 2;   // q,k,v contiguous
    u16* kbuf    = (u16*)p;             p += (size_t)NTOK * D_ * 2;
    u16* vbuf    = (u16*)p;             p += (size_t)NTOK * D_ * 2;
    u16* ybuf    = (u16*)p;             p += (size_t)NTOK * D_ * 2;
    u16* ff      = (u16*)p;             p += (size_t)NTOK * DF_ * 2;
    u16* WqkvT   = (u16*)p;             p += (size_t)L_ * 768 * D_ * 2;
    u16* WoT     = (u16*)p;             p += (size_t)L_ * D_ * D_ * 2;
    u16* W1T     = (u16*)p;             p += (size_t)L_ * D_ * DF_ * 2;
    u16* W2T     = (u16*)p;             p += (size_t)L_ * DF_ * D_ * 2;
    u16* hWT     = (u16*)p;             p += (size_t)V_ * D_ * 2;

    // weight prep
    twb4_kernel<<<dim3(8, 8, 16), 256, 0, stream>>>(Wq, Wk, Wv, Wo, WqkvT, WoT);
    twb_kernel<<<dim3(32, 8, 4), 256, 0, stream>>>(W1, W1T, D_, DF_);
    twb_kernel<<<dim3(8, 32, 4), 256, 0, stream>>>(W2, W2T, DF_, D_);
    twb_kernel<<<dim3(1000, 8, 1), 256, 0, stream>>>(hW, hWT, D_, V_);

    embed_ln_kernel<<<NTOK, 256, 0, stream>>>(idx, tok, pos, ln1g, ln1b, x, hbuf);

    dim3 gQkv(768 / 64, NTOK / 64);      // (12, 64)
    dim3 gLN(1, NTOK / 32);              // (1, 128)
    dim3 gFF1(DF_ / 64, NTOK / 64);      // (16, 64)
    dim3 gHead(V_ / 128, NTOK / 128);    // (250, 32)
    dim3 gAttn(T_ / 64, B_ * H_);        // (32, 8)

    for (int l = 0; l < L_; l++) {
        mfma_gemm<64, 64, 1><<<gQkv, 256, 0, stream>>>(
            hbuf, WqkvT + (size_t)l * 768 * D_, bq + l * D_, bk + l * D_, bv + l * D_,
            nullptr, nullptr, nullptr, nullptr, qbuf, NTOK, 768, D_);
        attn_kernel<<<gAttn, 256, 0, stream>>>(qbuf, kbuf, vbuf, ybuf);
        mfma_gemm<32, 256, 4><<<gLN, 256, 0, stream>>>(
            ybuf, WoT + (size_t)l * D_ * D_, bo + l * D_, nullptr, nullptr,
            ln2g + l * D_, ln2b + l * D_, x, x, hbuf, NTOK, D_, D_);
        mfma_gemm<64, 64, 3><<<gFF1, 256, 0, stream>>>(
            hbuf, W1T + (size_t)l * D_ * DF_, b1 + l * DF_, nullptr, nullptr,
            nullptr, nullptr, nullptr, nullptr, ff, NTOK, DF_, D_);
        const float* ng = (l < L_ - 1) ? ln1g + (l + 1) * D_ : lnfg;
        const float* nb = (l < L_ - 1) ? ln1b + (l + 1) * D_ : lnfb;
        mfma_gemm<32, 256, 4><<<gLN, 256, 0, stream>>>(
            ff, W2T + (size_t)l * DF_ * D_, b2 + l * D_, nullptr, nullptr,
            ng, nb, x, x, hbuf, NTOK, D_, DF_);
    }

    mfma_gemm<128, 128, 0><<<gHead, 256, 0, stream>>>(
        hbuf, hWT, hb, nullptr, nullptr, nullptr, nullptr, nullptr,
        (float*)d_out, nullptr, NTOK, V_, D_);
}